// Round 7
// baseline (121.148 us; speedup 1.0000x reference)
//
#include <hip/hip_runtime.h>
#include <math.h>

#define DET 512
#define NA  180
#define OUT 362    // floor(sqrt(512^2/2))
#define RAD 181    // OUT/2

#define NSPLIT 3   // angle partitions per (b, tile)
#define APB    60  // angles per block (NA / NSPLIT)
#define FTP_LD 516 // float2 stride per filtered line (>= 513)

constexpr double PI_D = 3.14159265358979323846;

// ---------------------------------------------------------------------------
// Compile-time trig table. Index ONLY with block/loop-uniform values.
// ---------------------------------------------------------------------------
constexpr double tsin(double x) {
    double x2 = x * x;
    return x * (1.0 + x2 * (-1.0/6 + x2 * (1.0/120 + x2 * (-1.0/5040 +
               x2 * (1.0/362880 + x2 * (-1.0/39916800))))));
}
constexpr double tcos(double x) {
    double x2 = x * x;
    return 1.0 + x2 * (-0.5 + x2 * (1.0/24 + x2 * (-1.0/720 +
               x2 * (1.0/40320 + x2 * (-1.0/3628800)))));
}

struct alignas(16) Trig { float c[NA]; float s[NA]; };
constexpr Trig make_trig() {
    Trig t{};
    constexpr double r = PI_D / 180.0;
    for (int k = 0; k < NA; ++k) {
        double c, s;
        if (k <= 45)       { c =  tcos(k * r);          s =  tsin(k * r); }
        else if (k <= 90)  { c =  tsin((90 - k) * r);   s =  tcos((90 - k) * r); }
        else if (k <= 135) { c = -tsin((k - 90) * r);   s =  tcos((k - 90) * r); }
        else               { c = -tcos((180 - k) * r);  s =  tsin((180 - k) * r); }
        t.c[k] = (float)c; t.s[k] = (float)s;
    }
    return t;
}
__device__ constexpr Trig TRIG = make_trig();

// ---------------------------------------------------------------------------
// Ramp-filter weight table, parity-blocked conv:
// w[h][ui][di], m = 8*(ui-63) + 2*(di-3) - 1 + 2*h (always odd), w = -2/(pi*m)^2
// ---------------------------------------------------------------------------
struct alignas(16) WTab { float w[2 * 127 * 8]; };
constexpr WTab make_wtab() {
    WTab t{};
    for (int h = 0; h < 2; ++h)
        for (int ui = 0; ui < 127; ++ui)
            for (int di = 0; di < 8; ++di) {
                int m = 8 * (ui - 63) + 2 * (di - 3) - 1 + 2 * h;
                double md = (double)m;
                t.w[(h * 127 + ui) * 8 + di] =
                    (float)(-2.0 / (PI_D * PI_D * md * md));
            }
    return t;
}
__device__ constexpr WTab WTAB = make_wtab();

// ---------------------------------------------------------------------------
// Kernel 1: ramp filter, parity-blocked conv, u-loop split across two wave
// segments (halved latency-bound critical path), LDS float4 reduce, output
// written as PAIRS: ftp[k] = (f[k], f[k+1]) so backprojection does one
// aligned 8B gather per interp. Also zeroes a slice of d_out.
// Thread map (256): half = t>>7 (0: even outputs, 1: odd), wseg = (t>>6)&1
// (u-range half), tp = t&63 (output block).
// ---------------------------------------------------------------------------
__global__ __launch_bounds__(256) void ramp_filter_kernel(
        const float* __restrict__ x, float2* __restrict__ ftp,
        float* __restrict__ out, int n4, int pb4) {
    const int bx = blockIdx.x;
    const int b  = blockIdx.y;
    const int t  = threadIdx.x;   // 0..255

    // XCD-locality swizzle: blocks with equal bx%8 get consecutive angles.
    const int rr = bx & 7, qq = bx >> 3;
    const int a  = 22 * rr + min(rr, 4) + qq;

    // --- fold in zeroing of d_out (atomicAdd target for kernel 2) ---
    {
        float4* oz = (float4*)out;
        const float4 z4 = make_float4(0.f, 0.f, 0.f, 0.f);
        const int base4 = (b * NA + bx) * pb4;
        for (int i = t; i < pb4; i += 256) {
            int idx = base4 + i;
            if (idx < n4) oz[idx] = z4;
        }
    }

    __shared__ float Ef[768];        // even samples, 256 zero floats each side
    __shared__ float Of[768];        // odd samples
    __shared__ float4 Rbuf[2][64];   // partials from wseg=1

    Ef[t] = 0.f;  Ef[512 + t] = 0.f;
    Of[t] = 0.f;  Of[512 + t] = 0.f;

    // x is (B,1,DET,NA): column (b,:,a); deinterleave by parity
    const float* xc = x + (size_t)(b * DET) * NA + a;
    float ev = xc[(2 * t) * NA];
    float ov = xc[(2 * t + 1) * NA];
    Ef[256 + t] = ev;
    Of[256 + t] = ov;
    __syncthreads();

    const int half = __builtin_amdgcn_readfirstlane(t >> 7);
    const int wseg = __builtin_amdgcn_readfirstlane((t >> 6) & 1);
    const int tp   = t & 63;
    const float4* src4  = (const float4*)(half ? Ef : Of);  // opposite parity
    const float4* self4 = (const float4*)(half ? Of : Ef);
    const float* __restrict__ Wh = WTAB.w + half * (127 * 8);

    float acc0 = 0.f, acc1 = 0.f, acc2 = 0.f, acc3 = 0.f;
    const int uiBeg = wseg ? 64 : 0;
    const int uiEnd = wseg ? 127 : 64;
    #pragma unroll 2
    for (int ui = uiBeg; ui < uiEnd; ++ui) {
        const float4 w0 = *(const float4*)&Wh[ui * 8];      // s_load (uniform)
        const float4 w1 = *(const float4*)&Wh[ui * 8 + 4];
        float4 s4 = src4[tp + (127 - ui)];
        acc0 = fmaf(s4.x, w0.w, fmaf(s4.y, w0.z, fmaf(s4.z, w0.y, fmaf(s4.w, w0.x, acc0))));
        acc1 = fmaf(s4.x, w1.x, fmaf(s4.y, w0.w, fmaf(s4.z, w0.z, fmaf(s4.w, w0.y, acc1))));
        acc2 = fmaf(s4.x, w1.y, fmaf(s4.y, w1.x, fmaf(s4.z, w0.w, fmaf(s4.w, w0.z, acc2))));
        acc3 = fmaf(s4.x, w1.z, fmaf(s4.y, w1.y, fmaf(s4.z, w1.x, fmaf(s4.w, w0.w, acc3))));
    }

    if (wseg) {
        Rbuf[half][tp] = make_float4(acc0, acc1, acc2, acc3);
    } else {
        float4 sf = self4[64 + tp];              // self term 0.5*x[d]
        acc0 = fmaf(0.5f, sf.x, acc0);
        acc1 = fmaf(0.5f, sf.y, acc1);
        acc2 = fmaf(0.5f, sf.z, acc2);
        acc3 = fmaf(0.5f, sf.w, acc3);
    }
    __syncthreads();

    if (!wseg) {
        float4 r = Rbuf[half][tp];
        acc0 += r.x; acc1 += r.y; acc2 += r.z; acc3 += r.w;

        // scatter into pair buffer: slot k gets .x = f[k] (from d=k owner)
        // and .y = f[k+1] (from d=k+1 owner) — disjoint 4B words, no race.
        float2* fp = ftp + (size_t)(b * NA + a) * FTP_LD;
        const int d0 = 8 * tp + half;            // outputs d0, d0+2, d0+4, d0+6
        fp[d0].x = acc0;  if (d0 > 0) fp[d0 - 1].y = acc0;
        fp[d0 + 2].x = acc1;  fp[d0 + 1].y = acc1;
        fp[d0 + 4].x = acc2;  fp[d0 + 3].y = acc2;
        fp[d0 + 6].x = acc3;  fp[d0 + 5].y = acc3;
        if (d0 + 6 == 511) fp[511].y = 0.0f;     // f[512] = 0 sentinel
    }
}

// ---------------------------------------------------------------------------
// Kernel 2: backprojection, zero LDS: one aligned global 8B gather per
// interp from the pair buffer (per-wave address span ~122 B -> 2-3 cache
// lines, L1-resident). No barriers in the main loop.
// ---------------------------------------------------------------------------
__device__ __forceinline__ float interp_fast(const float2* __restrict__ L, float pos) {
    float fr = __builtin_amdgcn_fractf(pos);
    int   i0 = (int)pos;                 // trunc == floor (pos > 0)
    float2 g = L[i0];                    // (f[i0], f[i0+1])
    return fmaf(fr, g.y - g.x, g.x);
}
__device__ __forceinline__ float interp_masked(const float2* __restrict__ L, float pos) {
    float v = interp_fast(L, pos);
    return pos <= (float)(DET - 1) ? v : 0.0f;
}

__global__ __launch_bounds__(256) void backproject_kernel(
        const float2* __restrict__ ftp, float* __restrict__ out) {
    const int bz = blockIdx.z;
    const int b  = bz / NSPLIT;
    const int sp = bz - b * NSPLIT;
    const int r0 = blockIdx.y * 32;
    const int c0 = blockIdx.x * 32;
    const int tid = threadIdx.x;
    const int tx = tid & 15;
    const int ty = tid >> 4;

    // guard pixels clamp coords (stores guarded off); pos stays in (0, 512)
    const float xpr = (float)(min(r0 + ty, OUT - 1) - RAD);
    const float ypr = (float)(min(c0 + tx, OUT - 1) - RAD);

    float a00 = 0.0f, a01 = 0.0f, a10 = 0.0f, a11 = 0.0f;

    const float2* baseP = ftp + (size_t)(b * NA + sp * APB) * FTP_LD;
    const int abase = sp * APB;

    auto run = [&](auto&& interp) {
        #pragma unroll 4
        for (int i = 0; i < APB; ++i) {
            const float cv = TRIG.c[abase + i];
            const float sv = TRIG.s[abase + i];
            const float2* Lp = baseP + (size_t)i * FTP_LD;
            // pos = ypr*cos - xpr*sin + det/2
            float p00 = fmaf(ypr, cv, fmaf(xpr, -sv, 256.0f));
            float p01 = fmaf(16.0f, cv, p00);       // col+16
            float p10 = fmaf(-16.0f, sv, p00);      // row+16
            float p11 = fmaf(-16.0f, sv, p01);      // row+16, col+16
            a00 += interp(Lp, p00);
            a01 += interp(Lp, p01);
            a10 += interp(Lp, p10);
            a11 += interp(Lp, p11);
        }
    };

    // Block-uniform mask elision: integer pixels with |off|<=181 can't land
    // in (254.56, 255], so radius^2 <= 255^2 guarantees pos in [1,511].
    {
        float drm = fmaxf(fabsf((float)(r0 - RAD)),
                          fabsf((float)(min(r0 + 31, OUT - 1) - RAD)));
        float dcm = fmaxf(fabsf((float)(c0 - RAD)),
                          fabsf((float)(min(c0 + 31, OUT - 1) - RAD)));
        if (drm * drm + dcm * dcm <= 65025.0f)   // 255^2
            run([](const float2* __restrict__ L, float p) { return interp_fast(L, p); });
        else
            run([](const float2* __restrict__ L, float p) { return interp_masked(L, p); });
    }

    const float scale = (float)(PI_D / (2.0 * NA));
    const int r = r0 + ty;
    const int c = c0 + tx;
    float* ob = out + b * OUT * OUT;
    if (r < OUT) {
        if (c < OUT)      atomicAdd(&ob[r * OUT + c],      a00 * scale);
        if (c + 16 < OUT) atomicAdd(&ob[r * OUT + c + 16], a01 * scale);
    }
    if (r + 16 < OUT) {
        if (c < OUT)      atomicAdd(&ob[(r + 16) * OUT + c],      a10 * scale);
        if (c + 16 < OUT) atomicAdd(&ob[(r + 16) * OUT + c + 16], a11 * scale);
    }
}

extern "C" void kernel_launch(void* const* d_in, const int* in_sizes, int n_in,
                              void* d_out, int out_size, void* d_ws, size_t ws_size,
                              hipStream_t stream) {
    const float* x = (const float*)d_in[0];
    float2* ftp = (float2*)d_ws;   // B*NA*FTP_LD*8 = ~3 MB scratch
    float* out  = (float*)d_out;

    const int B = in_sizes[0] / (DET * NA);   // 4

    const int n4  = out_size / 4;                       // float4 count
    const int pb4 = (n4 + NA * B - 1) / (NA * B);       // float4s zeroed/block

    ramp_filter_kernel<<<dim3(NA, B), 256, 0, stream>>>(x, ftp, out, n4, pb4);
    backproject_kernel<<<dim3((OUT + 31) / 32, (OUT + 31) / 32, B * NSPLIT),
                         256, 0, stream>>>(ftp, out);
}